// Round 4
// baseline (6645.657 us; speedup 1.0000x reference)
//
#include <hip/hip_runtime.h>
#include <stdint.h>

// LSTM N=32, T=2048, D=H=512. Persistent kernel, 8 groups x 32 WGs (grid=256=#CUs,
// co-resident). Each WG owns 16 hidden units (64 gate rows); weights stationary in
// VGPR MFMA A-fragments, rows ordered unit*4+gate. x and h split hi/lo bf16
// (two MFMA chains) for ~f32 accuracy.
//
// R7: ISOLATION EXPERIMENT. Exactly R3's proven all-MALL (sc0 sc1) scope for
// every cross-WG access (h data, flags, pack barrier). Single delta vs R3:
// per-WG monotone flag dwords replace the serialized 32-RMW atomic counter.
//   producer: store h (MALL) -> vmcnt(0) -> store own flag dword = t+2 (MALL)
//   consumer: wave0 lanes 0..31 poll all 32 flags (one 128B coalesced load)
//             until all >= t+1, then __syncthreads, then load h from MALL.
// No sc0-only fast path, no probe, no xcc (those are the other suspect from
// R5/R6's failures and are removed to discriminate). Spin budget guarantees
// termination. Compute path identical to R3.

#define T_STEPS 2048
#define HD 512
#define NBATCH 32
#define XSROW 516   // u32 row stride: 516 % 32 == 4 -> conflict-free-ish swizzle

typedef __attribute__((ext_vector_type(8))) short short8;
typedef __attribute__((ext_vector_type(4))) float f32x4;
typedef __attribute__((ext_vector_type(4))) uint u32x4;

static __device__ __forceinline__ uint bf_rne(float f) {
    uint u = __builtin_bit_cast(uint, f);
    return (u + 0x7FFFu + ((u >> 16) & 1u)) >> 16;
}
static __device__ __forceinline__ float bf_f(uint h) {
    return __builtin_bit_cast(float, h << 16);
}
// f32 -> (bf16_hi<<16) | bf16_lo
static __device__ __forceinline__ uint packsplit(float f) {
    uint hi = bf_rne(f);
    uint lo = bf_rne(f - bf_f(hi));
    return (hi << 16) | lo;
}

// Build hi/lo B-fragments (8 bf16 each) from 8 packed u32 (consecutive k).
static __device__ __forceinline__ void buildfrag(const uint* p, short8& bh, short8& bl) {
    uint4 w0 = *(const uint4*)p;
    uint4 w1 = *(const uint4*)(p + 4);
    uint4 hi, lo;
    hi.x = __builtin_amdgcn_perm(w0.y, w0.x, 0x07060302u);
    hi.y = __builtin_amdgcn_perm(w0.w, w0.z, 0x07060302u);
    hi.z = __builtin_amdgcn_perm(w1.y, w1.x, 0x07060302u);
    hi.w = __builtin_amdgcn_perm(w1.w, w1.z, 0x07060302u);
    lo.x = __builtin_amdgcn_perm(w0.y, w0.x, 0x05040100u);
    lo.y = __builtin_amdgcn_perm(w0.w, w0.z, 0x05040100u);
    lo.z = __builtin_amdgcn_perm(w1.y, w1.x, 0x05040100u);
    lo.w = __builtin_amdgcn_perm(w1.w, w1.z, 0x05040100u);
    bh = __builtin_bit_cast(short8, hi);
    bl = __builtin_bit_cast(short8, lo);
}

static __device__ __forceinline__ float sigf(float v) { return 1.f / (1.f + __expf(-v)); }
static __device__ __forceinline__ float tanhfast(float v) { return 2.f / (1.f + __expf(-2.f * v)) - 1.f; }

// ---- MALL-coherent (device/system-scope) ops: sc0 sc1 bypass L1/L2 ----
static __device__ __forceinline__ void st_mall4(uint* p, u32x4 v) {
    asm volatile("global_store_dwordx4 %0, %1, off sc0 sc1" :: "v"(p), "v"(v) : "memory");
}
static __device__ __forceinline__ void st_mall1(uint* p, uint v) {
    asm volatile("global_store_dword %0, %1, off sc0 sc1" :: "v"(p), "v"(v) : "memory");
}
static __device__ __forceinline__ uint ld_u32_dev(const uint* p) {
    uint v;
    asm volatile("global_load_dword %0, %1, off sc0 sc1\n\t"
                 "s_waitcnt vmcnt(0)" : "=v"(v) : "v"(p) : "memory");
    return v;
}
// issue two 16B loads (no wait) — results must not be read until wait_tied2
static __device__ __forceinline__ void ld_mall_issue2(const uint* p0, const uint* p1,
                                                      u32x4& a, u32x4& b) {
    asm volatile("global_load_dwordx4 %0, %2, off sc0 sc1\n\t"
                 "global_load_dwordx4 %1, %3, off sc0 sc1"
                 : "=&v"(a), "=&v"(b) : "v"(p0), "v"(p1) : "memory");
}
static __device__ __forceinline__ void wait_tied2(u32x4& a, u32x4& b) {
    asm volatile("s_waitcnt vmcnt(0)" : "+v"(a), "+v"(b) :: "memory");
}
static __device__ __forceinline__ void waitvm0() {
    asm volatile("s_waitcnt vmcnt(0)" ::: "memory");
}

__global__ __launch_bounds__(256, 1) void lstm_pers(
    const float* __restrict__ x, const float* __restrict__ Wih,
    const float* __restrict__ bih, const float* __restrict__ Whh,
    const float* __restrict__ bhh, float* __restrict__ y,
    uint* __restrict__ hbuf, uint* __restrict__ cnt,
    uint* __restrict__ xpk, int xpre)
{
    __shared__ uint xsh[4 * XSROW];   // shared x staging (4 batch rows, packed)
    __shared__ uint hs[4 * XSROW];    // shared h staging
    __shared__ uint hpub[64];         // publish gather: [batch][unit_local]

    const int b   = blockIdx.x;
    const int g   = b & 7;
    const int w   = b >> 3;
    const int tid = threadIdx.x;
    const int wv  = tid >> 6;
    const int l   = tid & 63;
    const int q   = l >> 4;
    const int m   = l & 15;

    // ---- stationary weight A-fragments: rows ordered unit*4+gate ----
    const int gateA = m & 3, ulA = m >> 2;
    const int Arow  = gateA * HD + ((w << 4) + (wv << 2) + ulA);
    short8 wf[32];
#pragma unroll
    for (int kt = 0; kt < 32; ++kt) {
        const int k0 = kt * 32 + q * 8;
        const float* src = (k0 < HD) ? (Wih + (size_t)Arow * HD + k0)
                                     : (Whh + (size_t)Arow * HD + (k0 - HD));
        float4 a  = ((const float4*)src)[0];
        float4 c4 = ((const float4*)src)[1];
        uint4 uu;
        uu.x = bf_rne(a.x)  | (bf_rne(a.y)  << 16);
        uu.y = bf_rne(a.z)  | (bf_rne(a.w)  << 16);
        uu.z = bf_rne(c4.x) | (bf_rne(c4.y) << 16);
        uu.w = bf_rne(c4.z) | (bf_rne(c4.w) << 16);
        wf[kt] = __builtin_bit_cast(short8, uu);
    }

    const int unitC = (w << 4) + (wv << 2) + q;
    float bias_[4];
#pragma unroll
    for (int i = 0; i < 4; ++i) bias_[i] = bih[i * HD + unitC] + bhh[i * HD + unitC];

    const bool act = (m < 4);
    uint* const fgp = cnt + (g << 5);   // flags: 32 dwords = ONE 128B line per group

    int budget = 1 << 21;   // global spin budget: guarantees termination

    // ---- prologue: group-local x -> packed hi|lo bf16 in xpk (if ws fits) ----
    if (xpre) {
        const size_t base = (size_t)(g * 4) * T_STEPS * HD + (size_t)w * 131072u;
#pragma unroll 4
        for (int i = 0; i < 128; ++i) {
            const size_t off = base + (size_t)i * 1024 + (size_t)tid * 4;
            float4 v4 = *(const float4*)(x + off);
            u32x4 u;
            u.x = packsplit(v4.x); u.y = packsplit(v4.y);
            u.z = packsplit(v4.z); u.w = packsplit(v4.w);
            st_mall4(xpk + off, u);
        }
        waitvm0();
    }
    __syncthreads();

    // ---- group barrier (pack fence): flag=1, wait all 32 flags >= 1 ----
    if (tid == 0) st_mall1(fgp + w, 1u);
    if (tid < 64) {
        const int li = l & 31;
        for (;;) {
            uint f = ld_u32_dev(fgp + li);
            if (__all((l >= 32) | (f >= 1u))) break;
            if (--budget <= 0) break;
        }
    }
    __syncthreads();

    // stage one batch row (row wv) of x(tt) into shared xsh
    auto stage_x = [&](int tt) {
        const size_t roff = ((size_t)(g * 4 + wv) * T_STEPS + tt) * HD;
        if (xpre) {
            const uint* xp = xpk + roff;
            u32x4 a = *(const u32x4*)(xp + l * 4);
            u32x4 c = *(const u32x4*)(xp + 256 + l * 4);
            *(u32x4*)&xsh[wv * XSROW + l * 4] = a;
            *(u32x4*)&xsh[wv * XSROW + 256 + l * 4] = c;
        } else {
            const float* xp = x + roff;
#pragma unroll
            for (int j2 = 0; j2 < 2; ++j2) {
                const int k0 = j2 * 256 + l * 4;
                float4 t4 = *(const float4*)(xp + k0);
                u32x4 u;
                u.x = packsplit(t4.x); u.y = packsplit(t4.y);
                u.z = packsplit(t4.z); u.w = packsplit(t4.w);
                *(u32x4*)&xsh[wv * XSROW + k0] = u;
            }
        }
    };

    const f32x4 zero4 = {0.f, 0.f, 0.f, 0.f};
    float cst = 0.f;

    stage_x(0);
    __syncthreads();

    for (int t = 0; t < T_STEPS; ++t) {
        f32x4 a0 = zero4, a1 = zero4, b0 = zero4, b1 = zero4;
        u32x4 ha, hb;

        if (t > 0) {
            // need h(t-1) from all 32 WGs: their flag = (t-1)+2 = t+1
            if (tid < 64) {
                const int  li   = l & 31;
                const uint want = (uint)t + 1u;
                for (;;) {
                    uint f = ld_u32_dev(fgp + li);
                    if (__all((l >= 32) | (f >= want))) break;
                    if (--budget <= 0) break;
                }
            }
            __syncthreads();
            const uint* hp = hbuf + (size_t)(((t - 1) & 1) * NBATCH + g * 4 + wv) * HD;
            ld_mall_issue2(hp + l * 4, hp + 256 + l * 4, ha, hb);   // issue, no wait
        }

        // x-projection MFMA (reads xsh staged last iter) — hides h-load latency
#pragma unroll
        for (int kt = 0; kt < 16; ++kt) {
            short8 bh, bl;
            buildfrag(&xsh[(l & 3) * XSROW + kt * 32 + q * 8], bh, bl);
            if (kt & 1) {
                a1 = __builtin_amdgcn_mfma_f32_16x16x32_bf16(wf[kt], bh, a1, 0, 0, 0);
                b1 = __builtin_amdgcn_mfma_f32_16x16x32_bf16(wf[kt], bl, b1, 0, 0, 0);
            } else {
                a0 = __builtin_amdgcn_mfma_f32_16x16x32_bf16(wf[kt], bh, a0, 0, 0, 0);
                b0 = __builtin_amdgcn_mfma_f32_16x16x32_bf16(wf[kt], bl, b0, 0, 0, 0);
            }
        }

        if (t > 0) {
            wait_tied2(ha, hb);
            *(u32x4*)&hs[wv * XSROW + l * 4] = ha;
            *(u32x4*)&hs[wv * XSROW + 256 + l * 4] = hb;
            __syncthreads();
#pragma unroll
            for (int kt = 0; kt < 16; ++kt) {
                short8 bh, bl;
                buildfrag(&hs[(l & 3) * XSROW + kt * 32 + q * 8], bh, bl);
                if (kt & 1) {
                    a1 = __builtin_amdgcn_mfma_f32_16x16x32_bf16(wf[16 + kt], bh, a1, 0, 0, 0);
                    b1 = __builtin_amdgcn_mfma_f32_16x16x32_bf16(wf[16 + kt], bl, b1, 0, 0, 0);
                } else {
                    a0 = __builtin_amdgcn_mfma_f32_16x16x32_bf16(wf[16 + kt], bh, a0, 0, 0, 0);
                    b0 = __builtin_amdgcn_mfma_f32_16x16x32_bf16(wf[16 + kt], bl, b0, 0, 0, 0);
                }
            }
        }

        const float v0 = a0.x + a1.x + b0.x + b1.x + bias_[0];   // i
        const float v1 = a0.y + a1.y + b0.y + b1.y + bias_[1];   // f
        const float v2 = a0.z + a1.z + b0.z + b1.z + bias_[2];   // o
        const float v3 = a0.w + a1.w + b0.w + b1.w + bias_[3];   // g
        const float ig = sigf(v0), fg = sigf(v1), og = sigf(v2), gg = tanhfast(v3);
        cst = fg * cst + ig * gg;
        const float hv = og * tanhfast(cst);

        if (act) hpub[m * 16 + ((wv << 2) | q)] = packsplit(hv);
        __syncthreads();   // hpub visible to wave0; xsh reads (x-MFMA) all done

        if (tid < 64) {
            // wave0 publishes the WG's 64 h values (4 batches x 16 units, contiguous),
            // then its own flag dword = t+2 (monotone; no atomics, no RMW serialization)
            const uint p = hpub[tid];
            uint* dst = hbuf + (size_t)((t & 1) * NBATCH + g * 4 + (tid >> 4)) * HD
                        + (w << 4) + (tid & 15);
            st_mall1(dst, p);
            waitvm0();
            if (tid == 0) st_mall1(fgp + w, (uint)t + 2u);
            const float yv = __builtin_bit_cast(float, p & 0xFFFF0000u)
                           + __builtin_bit_cast(float, p << 16);
            y[((size_t)(g * 4 + (tid >> 4)) * T_STEPS + t) * HD + (w << 4) + (tid & 15)] = yv;
        }

        stage_x(t + 1 < T_STEPS ? t + 1 : T_STEPS - 1);
        // next iteration's poll-__syncthreads protects xsh/hs reuse
    }
}

extern "C" void kernel_launch(void* const* d_in, const int* in_sizes, int n_in,
                              void* d_out, int out_size, void* d_ws, size_t ws_size,
                              hipStream_t stream) {
    (void)in_sizes; (void)n_in; (void)out_size;
    const float* x   = (const float*)d_in[0];
    const float* Wih = (const float*)d_in[1];
    const float* bih = (const float*)d_in[2];
    const float* Whh = (const float*)d_in[3];
    const float* bhh = (const float*)d_in[4];
    float* y = (float*)d_out;

    uint* hbuf = (uint*)d_ws;                              // 128 KiB (2 slots x 32 x 512)
    uint* cnt  = (uint*)((char*)d_ws + 131072);            // 2 KiB flags
    uint* xpk  = (uint*)((char*)d_ws + 131072 + 2048);     // packed x, 128 MiB
    const int xpre = (ws_size >= 134350848ull) ? 1 : 0;
    hipMemsetAsync(cnt, 0, 2048, stream);
    lstm_pers<<<dim3(256), dim3(256), 0, stream>>>(x, Wih, bih, Whh, bhh, y,
                                                   hbuf, cnt, xpk, xpre);
}

// Round 5
// 5631.750 us; speedup vs baseline: 1.1800x; 1.1800x over previous
//
#include <hip/hip_runtime.h>
#include <stdint.h>

// LSTM N=32, T=2048, D=H=512. Persistent kernel, 8 groups x 32 WGs (grid=256=#CUs,
// co-resident). Each WG owns 16 hidden units (64 gate rows); weights stationary in
// VGPR MFMA A-fragments, rows ordered unit*4+gate. x and h split hi/lo bf16
// (two MFMA chains) for ~f32 accuracy.
//
// R8: tagged-data h exchange (seqlock-free). Each h element is an 8B pair
// {packed hi|lo bf16, tag=t+1} stored with ONE atomic global_store_dwordx2
// sc0 sc1, fire-and-forget from the activation lanes directly (no LDS hpub
// gather, no wave0 publish, no vmcnt ack, no flag store, no flag poll).
// Consumers poll the DATA: speculatively issue 4 tagged dwordx4 loads before
// the x-MFMA phase (hides latency), then check all tags == t, re-loading only
// stale data. Ping-pong slots + exact-tag-match are safe: no WG can publish
// h(t+1) before every WG has fully read h(t-1) (transitive step ordering), and
// hbuf is memset per launch so stale tags cannot leak across launches.
// R5/R6 post-mortem: sc0-only (XCD-L2) exchange is NOT reliably coherent
// cross-WG (vmcnt acks locally; probe false-passed on slack) -> all cross-WG
// traffic stays sc0 sc1 (MALL), which R3/R7 proved correct.

#define T_STEPS 2048
#define HD 512
#define NBATCH 32
#define XSROW 516   // u32 row stride: 516 % 32 == 4 -> conflict-free-ish swizzle

typedef __attribute__((ext_vector_type(8))) short short8;
typedef __attribute__((ext_vector_type(4))) float f32x4;
typedef __attribute__((ext_vector_type(4))) uint u32x4;
typedef __attribute__((ext_vector_type(2))) uint u32x2;

static __device__ __forceinline__ uint bf_rne(float f) {
    uint u = __builtin_bit_cast(uint, f);
    return (u + 0x7FFFu + ((u >> 16) & 1u)) >> 16;
}
static __device__ __forceinline__ float bf_f(uint h) {
    return __builtin_bit_cast(float, h << 16);
}
// f32 -> (bf16_hi<<16) | bf16_lo
static __device__ __forceinline__ uint packsplit(float f) {
    uint hi = bf_rne(f);
    uint lo = bf_rne(f - bf_f(hi));
    return (hi << 16) | lo;
}

// Build hi/lo B-fragments (8 bf16 each) from 8 packed u32 (consecutive k).
static __device__ __forceinline__ void buildfrag(const uint* p, short8& bh, short8& bl) {
    uint4 w0 = *(const uint4*)p;
    uint4 w1 = *(const uint4*)(p + 4);
    uint4 hi, lo;
    hi.x = __builtin_amdgcn_perm(w0.y, w0.x, 0x07060302u);
    hi.y = __builtin_amdgcn_perm(w0.w, w0.z, 0x07060302u);
    hi.z = __builtin_amdgcn_perm(w1.y, w1.x, 0x07060302u);
    hi.w = __builtin_amdgcn_perm(w1.w, w1.z, 0x07060302u);
    lo.x = __builtin_amdgcn_perm(w0.y, w0.x, 0x05040100u);
    lo.y = __builtin_amdgcn_perm(w0.w, w0.z, 0x05040100u);
    lo.z = __builtin_amdgcn_perm(w1.y, w1.x, 0x05040100u);
    lo.w = __builtin_amdgcn_perm(w1.w, w1.z, 0x05040100u);
    bh = __builtin_bit_cast(short8, hi);
    bl = __builtin_bit_cast(short8, lo);
}

static __device__ __forceinline__ float sigf(float v) { return 1.f / (1.f + __expf(-v)); }
static __device__ __forceinline__ float tanhfast(float v) { return 2.f / (1.f + __expf(-2.f * v)) - 1.f; }

// ---- MALL-coherent (device-scope) ops: sc0 sc1 bypass L1/L2 ----
static __device__ __forceinline__ void st_mall4(uint* p, u32x4 v) {
    asm volatile("global_store_dwordx4 %0, %1, off sc0 sc1" :: "v"(p), "v"(v) : "memory");
}
static __device__ __forceinline__ void st_mall2(uint* p, u32x2 v) {
    asm volatile("global_store_dwordx2 %0, %1, off sc0 sc1" :: "v"(p), "v"(v) : "memory");
}
static __device__ __forceinline__ void st_mall1(uint* p, uint v) {
    asm volatile("global_store_dword %0, %1, off sc0 sc1" :: "v"(p), "v"(v) : "memory");
}
static __device__ __forceinline__ uint ld_u32_dev(const uint* p) {
    uint v;
    asm volatile("global_load_dword %0, %1, off sc0 sc1\n\t"
                 "s_waitcnt vmcnt(0)" : "=v"(v) : "v"(p) : "memory");
    return v;
}
// issue four 16B tagged loads (no wait) — results unread until wait_tied4
static __device__ __forceinline__ void ld_mall_issue4(const uint* p0, const uint* p1,
                                                      const uint* p2, const uint* p3,
                                                      u32x4& a, u32x4& b, u32x4& c, u32x4& d) {
    asm volatile("global_load_dwordx4 %0, %4, off sc0 sc1\n\t"
                 "global_load_dwordx4 %1, %5, off sc0 sc1\n\t"
                 "global_load_dwordx4 %2, %6, off sc0 sc1\n\t"
                 "global_load_dwordx4 %3, %7, off sc0 sc1"
                 : "=&v"(a), "=&v"(b), "=&v"(c), "=&v"(d)
                 : "v"(p0), "v"(p1), "v"(p2), "v"(p3) : "memory");
}
static __device__ __forceinline__ void wait_tied4(u32x4& a, u32x4& b, u32x4& c, u32x4& d) {
    asm volatile("s_waitcnt vmcnt(0)" : "+v"(a), "+v"(b), "+v"(c), "+v"(d) :: "memory");
}
static __device__ __forceinline__ void waitvm0() {
    asm volatile("s_waitcnt vmcnt(0)" ::: "memory");
}
static __device__ __forceinline__ void waitlgkm0() {
    asm volatile("s_waitcnt lgkmcnt(0)" ::: "memory");
}

__global__ __launch_bounds__(256, 1) void lstm_pers(
    const float* __restrict__ x, const float* __restrict__ Wih,
    const float* __restrict__ bih, const float* __restrict__ Whh,
    const float* __restrict__ bhh, float* __restrict__ y,
    uint* __restrict__ hq, uint* __restrict__ cnt,
    uint* __restrict__ xpk, int xpre)
{
    __shared__ uint xsh[4 * XSROW];   // shared x staging (4 batch rows, packed)
    __shared__ uint hs[4 * XSROW];    // shared h staging (payloads, tags stripped)

    const int b   = blockIdx.x;
    const int g   = b & 7;
    const int w   = b >> 3;
    const int tid = threadIdx.x;
    const int wv  = tid >> 6;
    const int l   = tid & 63;
    const int q   = l >> 4;
    const int m   = l & 15;

    // ---- stationary weight A-fragments: rows ordered unit*4+gate ----
    const int gateA = m & 3, ulA = m >> 2;
    const int Arow  = gateA * HD + ((w << 4) + (wv << 2) + ulA);
    short8 wf[32];
#pragma unroll
    for (int kt = 0; kt < 32; ++kt) {
        const int k0 = kt * 32 + q * 8;
        const float* src = (k0 < HD) ? (Wih + (size_t)Arow * HD + k0)
                                     : (Whh + (size_t)Arow * HD + (k0 - HD));
        float4 a  = ((const float4*)src)[0];
        float4 c4 = ((const float4*)src)[1];
        uint4 uu;
        uu.x = bf_rne(a.x)  | (bf_rne(a.y)  << 16);
        uu.y = bf_rne(a.z)  | (bf_rne(a.w)  << 16);
        uu.z = bf_rne(c4.x) | (bf_rne(c4.y) << 16);
        uu.w = bf_rne(c4.z) | (bf_rne(c4.w) << 16);
        wf[kt] = __builtin_bit_cast(short8, uu);
    }

    const int unitC = (w << 4) + (wv << 2) + q;
    float bias_[4];
#pragma unroll
    for (int i = 0; i < 4; ++i) bias_[i] = bih[i * HD + unitC] + bhh[i * HD + unitC];

    const bool act = (m < 4);
    uint* const fgp = cnt + (g << 5);   // prologue flags: 32 dwords (one line/group)

    int budget = 1 << 21;   // global spin budget: guarantees termination

    // ---- prologue: group-local x -> packed hi|lo bf16 in xpk (if ws fits) ----
    if (xpre) {
        const size_t base = (size_t)(g * 4) * T_STEPS * HD + (size_t)w * 131072u;
#pragma unroll 4
        for (int i = 0; i < 128; ++i) {
            const size_t off = base + (size_t)i * 1024 + (size_t)tid * 4;
            float4 v4 = *(const float4*)(x + off);
            u32x4 u;
            u.x = packsplit(v4.x); u.y = packsplit(v4.y);
            u.z = packsplit(v4.z); u.w = packsplit(v4.w);
            st_mall4(xpk + off, u);
        }
        waitvm0();
    }
    __syncthreads();

    // ---- group barrier (pack fence): flag=1, wait all 32 flags >= 1 ----
    if (tid == 0) st_mall1(fgp + w, 1u);
    if (tid < 64) {
        const int li = l & 31;
        for (;;) {
            uint f = ld_u32_dev(fgp + li);
            if (__all((l >= 32) | (f >= 1u))) break;
            if (--budget <= 0) break;
        }
    }
    __syncthreads();

    // stage one batch row (row wv) of x(tt) into shared xsh
    auto stage_x = [&](int tt) {
        const size_t roff = ((size_t)(g * 4 + wv) * T_STEPS + tt) * HD;
        if (xpre) {
            const uint* xp = xpk + roff;
            u32x4 a = *(const u32x4*)(xp + l * 4);
            u32x4 c = *(const u32x4*)(xp + 256 + l * 4);
            *(u32x4*)&xsh[wv * XSROW + l * 4] = a;
            *(u32x4*)&xsh[wv * XSROW + 256 + l * 4] = c;
        } else {
            const float* xp = x + roff;
#pragma unroll
            for (int j2 = 0; j2 < 2; ++j2) {
                const int k0 = j2 * 256 + l * 4;
                float4 t4 = *(const float4*)(xp + k0);
                u32x4 u;
                u.x = packsplit(t4.x); u.y = packsplit(t4.y);
                u.z = packsplit(t4.z); u.w = packsplit(t4.w);
                *(u32x4*)&xsh[wv * XSROW + k0] = u;
            }
        }
    };

    const f32x4 zero4 = {0.f, 0.f, 0.f, 0.f};
    float cst = 0.f;

    stage_x(0);
    __syncthreads();

    for (int t = 0; t < T_STEPS; ++t) {
        f32x4 a0 = zero4, a1 = zero4, b0 = zero4, b1 = zero4;
        u32x4 va, vb, vc, vd;

        // tagged h row for this wave's batch: 512 pairs = 1024 dwords
        uint* const hp = hq + (size_t)(((t - 1) & 1) * NBATCH + g * 4 + wv) * (HD * 2);
        if (t > 0) {
            // speculative issue (no wait) — latency hidden under x-MFMA below
            ld_mall_issue4(hp + 4 * l, hp + 256 + 4 * l, hp + 512 + 4 * l,
                           hp + 768 + 4 * l, va, vb, vc, vd);
        }

        // x-projection MFMA (reads xsh staged last iter)
#pragma unroll
        for (int kt = 0; kt < 16; ++kt) {
            short8 bh, bl;
            buildfrag(&xsh[(l & 3) * XSROW + kt * 32 + q * 8], bh, bl);
            if (kt & 1) {
                a1 = __builtin_amdgcn_mfma_f32_16x16x32_bf16(wf[kt], bh, a1, 0, 0, 0);
                b1 = __builtin_amdgcn_mfma_f32_16x16x32_bf16(wf[kt], bl, b1, 0, 0, 0);
            } else {
                a0 = __builtin_amdgcn_mfma_f32_16x16x32_bf16(wf[kt], bh, a0, 0, 0, 0);
                b0 = __builtin_amdgcn_mfma_f32_16x16x32_bf16(wf[kt], bl, b0, 0, 0, 0);
            }
        }

        if (t > 0) {
            // data-poll: all 8 tags (4 loads x 2 pairs) must equal t
            wait_tied4(va, vb, vc, vd);
            const uint want = (uint)t;
            for (;;) {
                int ok = (va.y == want) & (va.w == want) & (vb.y == want) & (vb.w == want)
                       & (vc.y == want) & (vc.w == want) & (vd.y == want) & (vd.w == want);
                if (__all(ok)) break;
                if (--budget <= 0) break;
                ld_mall_issue4(hp + 4 * l, hp + 256 + 4 * l, hp + 512 + 4 * l,
                               hp + 768 + 4 * l, va, vb, vc, vd);
                wait_tied4(va, vb, vc, vd);
            }
            // strip tags -> hs (lane covers units {2l,2l+1} of each 128-unit block)
            *(u32x2*)&hs[wv * XSROW + 2 * l]       = (u32x2){va.x, va.z};
            *(u32x2*)&hs[wv * XSROW + 128 + 2 * l] = (u32x2){vb.x, vb.z};
            *(u32x2*)&hs[wv * XSROW + 256 + 2 * l] = (u32x2){vc.x, vc.z};
            *(u32x2*)&hs[wv * XSROW + 384 + 2 * l] = (u32x2){vd.x, vd.z};
            __syncthreads();
#pragma unroll
            for (int kt = 0; kt < 16; ++kt) {
                short8 bh, bl;
                buildfrag(&hs[(l & 3) * XSROW + kt * 32 + q * 8], bh, bl);
                if (kt & 1) {
                    a1 = __builtin_amdgcn_mfma_f32_16x16x32_bf16(wf[16 + kt], bh, a1, 0, 0, 0);
                    b1 = __builtin_amdgcn_mfma_f32_16x16x32_bf16(wf[16 + kt], bl, b1, 0, 0, 0);
                } else {
                    a0 = __builtin_amdgcn_mfma_f32_16x16x32_bf16(wf[16 + kt], bh, a0, 0, 0, 0);
                    b0 = __builtin_amdgcn_mfma_f32_16x16x32_bf16(wf[16 + kt], bl, b0, 0, 0, 0);
                }
            }
        } else {
            __syncthreads();   // t==0: order x-MFMA reads before stage_x writes
        }

        const float v0 = a0.x + a1.x + b0.x + b1.x + bias_[0];   // i
        const float v1 = a0.y + a1.y + b0.y + b1.y + bias_[1];   // f
        const float v2 = a0.z + a1.z + b0.z + b1.z + bias_[2];   // o
        const float v3 = a0.w + a1.w + b0.w + b1.w + bias_[3];   // g
        const float ig = sigf(v0), fg = sigf(v1), og = sigf(v2), gg = tanhfast(v3);
        cst = fg * cst + ig * gg;
        const float hv = og * tanhfast(cst);

        if (act) {
            // direct tagged publish from the activation lane: ONE atomic 8B store,
            // fire-and-forget (consumers validate via the tag; no ack, no flag)
            const uint p  = packsplit(hv);
            const int  bi = g * 4 + m;
            const int  un = (w << 4) + (wv << 2) + q;
            uint* dst = hq + (size_t)((t & 1) * NBATCH + bi) * (HD * 2) + un * 2;
            st_mall2(dst, (u32x2){p, (uint)t + 1u});
            y[((size_t)bi * T_STEPS + t) * HD + un] =
                __builtin_bit_cast(float, p & 0xFFFF0000u)
              + __builtin_bit_cast(float, p << 16);
        }

        stage_x(t + 1 < T_STEPS ? t + 1 : T_STEPS - 1);
        __syncthreads();   // xsh(t+1) staged before any wave's x-MFMA reads it
    }
}

extern "C" void kernel_launch(void* const* d_in, const int* in_sizes, int n_in,
                              void* d_out, int out_size, void* d_ws, size_t ws_size,
                              hipStream_t stream) {
    (void)in_sizes; (void)n_in; (void)out_size;
    const float* x   = (const float*)d_in[0];
    const float* Wih = (const float*)d_in[1];
    const float* bih = (const float*)d_in[2];
    const float* Whh = (const float*)d_in[3];
    const float* bhh = (const float*)d_in[4];
    float* y = (float*)d_out;

    // layout: tagged hbuf (2 slots x 32 x 512 x 8B = 256K) | cnt (2K) | xpk (128M)
    uint* hq  = (uint*)d_ws;
    uint* cnt = (uint*)((char*)d_ws + 262144);
    uint* xpk = (uint*)((char*)d_ws + 264192);
    const int xpre = (ws_size >= 264192ull + 134217728ull) ? 1 : 0;
    // zero tags + flags every launch (stale tags must never read as fresh)
    hipMemsetAsync(hq, 0, 264192, stream);
    lstm_pers<<<dim3(256), dim3(256), 0, stream>>>(x, Wih, bih, Whh, bhh, y,
                                                   hq, cnt, xpk, xpre);
}